// Round 2
// baseline (613.329 us; speedup 1.0000x reference)
//
#include <hip/hip_runtime.h>

#define B_ 256
#define T_ 128
#define I_ 2048
#define H_ 128
#define G_ 512   // 4*H
#define O_ 2

typedef _Float16 half8 __attribute__((ext_vector_type(8)));
typedef float f32x4 __attribute__((ext_vector_type(4)));

// ---------------- Wi -> Wi^T fp16 convert (Wt[n][k] = Wi[k][n]) ----------------
__global__ void wt_kernel(const float* __restrict__ Wi, _Float16* __restrict__ Wt) {
    int idx = blockIdx.x * 256 + threadIdx.x;   // 512*2048 total
    int n = idx >> 11;       // / 2048
    int k = idx & 2047;
    Wt[idx] = (_Float16)Wi[k * G_ + n];
}

// ---------------- xg = x @ Wi  (fp16 MFMA, fp32 accumulate) ----------------
#define BM 128
#define BN 128
#define BK 32
#define LDSW 40   // fp16 elems per LDS row (32 + 8 pad -> 80B rows, breaks bank conflicts)

__device__ __forceinline__ half8 pack_f16(const f32x4& a, const f32x4& b) {
    half8 r;
    r[0]=(_Float16)a[0]; r[1]=(_Float16)a[1]; r[2]=(_Float16)a[2]; r[3]=(_Float16)a[3];
    r[4]=(_Float16)b[0]; r[5]=(_Float16)b[1]; r[6]=(_Float16)b[2]; r[7]=(_Float16)b[3];
    return r;
}

__launch_bounds__(256, 2)
__global__ void gemm_xg(const float* __restrict__ X, const _Float16* __restrict__ Wt,
                        float* __restrict__ xg) {
    __shared__ _Float16 lds_a[BM * LDSW];
    __shared__ _Float16 lds_b[BN * LDSW];

    // XCD-aware swizzle: 1024 blocks, 8 XCDs -> 128 consecutive swz per XCD,
    // so the 4 column-tiles of a row-block share an XCD's L2 (A-panel reuse).
    int bid = blockIdx.x;
    int swz = (bid & 7) * 128 + (bid >> 3);
    int bm = swz >> 2;          // 0..255
    int bn = swz & 3;           // 0..3
    int m0 = bm * BM, n0 = bn * BN;

    const int t = threadIdx.x;
    const int row_s = t >> 1;           // 0..127 (staging row)
    const int kh    = (t & 1) << 4;     // 0 or 16 (k sub-chunk)

    const float*    aptr = X  + (size_t)(m0 + row_s) * I_ + kh;
    const _Float16* bptr = Wt + (size_t)(n0 + row_s) * I_ + kh;
    const int st_off = row_s * LDSW + kh;

    const int l  = t & 63;
    const int w  = t >> 6;
    const int wm = w >> 1, wn = w & 1;     // 2x2 waves, 64x64 each
    const int lr = l & 15;
    const int kq = (l >> 4) << 3;          // 0,8,16,24

    f32x4 acc[4][4];
    #pragma unroll
    for (int mi = 0; mi < 4; ++mi)
        #pragma unroll
        for (int ni = 0; ni < 4; ++ni)
            acc[mi][ni] = (f32x4){0.f, 0.f, 0.f, 0.f};

    for (int kt = 0; kt < I_ / BK; ++kt) {
        const int k0 = kt * BK;
        f32x4 a0 = *(const f32x4*)(aptr + k0 + 0);
        f32x4 a1 = *(const f32x4*)(aptr + k0 + 4);
        f32x4 a2 = *(const f32x4*)(aptr + k0 + 8);
        f32x4 a3 = *(const f32x4*)(aptr + k0 + 12);
        half8 b0 = *(const half8*)(bptr + k0);
        half8 b1 = *(const half8*)(bptr + k0 + 8);
        half8 pa0 = pack_f16(a0, a1);
        half8 pa1 = pack_f16(a2, a3);

        if (kt) __syncthreads();           // previous tile's reads done
        *(half8*)&lds_a[st_off]     = pa0;
        *(half8*)&lds_a[st_off + 8] = pa1;
        *(half8*)&lds_b[st_off]     = b0;
        *(half8*)&lds_b[st_off + 8] = b1;
        __syncthreads();

        half8 af[4], bf[4];
        #pragma unroll
        for (int mi = 0; mi < 4; ++mi)
            af[mi] = *(const half8*)&lds_a[(wm * 64 + mi * 16 + lr) * LDSW + kq];
        #pragma unroll
        for (int ni = 0; ni < 4; ++ni)
            bf[ni] = *(const half8*)&lds_b[(wn * 64 + ni * 16 + lr) * LDSW + kq];
        #pragma unroll
        for (int mi = 0; mi < 4; ++mi)
            #pragma unroll
            for (int ni = 0; ni < 4; ++ni)
                acc[mi][ni] = __builtin_amdgcn_mfma_f32_16x16x32_f16(af[mi], bf[ni], acc[mi][ni], 0, 0, 0);
    }

    // epilogue: D col = lane&15, row = (lane>>4)*4 + r  (m89-verified layout)
    #pragma unroll
    for (int mi = 0; mi < 4; ++mi) {
        #pragma unroll
        for (int ni = 0; ni < 4; ++ni) {
            const int col = n0 + wn * 64 + ni * 16 + lr;
            #pragma unroll
            for (int r = 0; r < 4; ++r) {
                const int row = m0 + wm * 64 + mi * 16 + (l >> 4) * 4 + r;
                xg[(size_t)row * G_ + col] = acc[mi][ni][r];
            }
        }
    }
}

// ---------------- LSTM scan + output head ----------------
__device__ __forceinline__ float sigmoidf_fast(float x) {
    return 1.f / (1.f + __expf(-x));
}
__device__ __forceinline__ float tanhf_fast(float x) {
    return 1.f - 2.f / (__expf(2.f * x) + 1.f);   // saturates correctly at +-1
}

__launch_bounds__(512, 2)
__global__ void lstm_scan(const float* __restrict__ xg, const float* __restrict__ Uh,
                          const float* __restrict__ bias, const float* __restrict__ Wout,
                          const float* __restrict__ bout, float* __restrict__ out) {
    __shared__ float h_lds[H_];
    __shared__ float z_lds[G_];
    const int b = blockIdx.x;     // batch row (sequences are independent)
    const int j = threadIdx.x;    // gate column 0..511

    // Uh column j held in registers: 128 VGPRs/thread
    float U[H_];
    #pragma unroll
    for (int k = 0; k < H_; ++k) U[k] = Uh[k * G_ + j];
    const float bj = bias[j];
    if (j < H_) h_lds[j] = 0.f;
    float c = 0.f;
    __syncthreads();

    const float* xgb = xg + (size_t)b * T_ * G_;
    for (int t = 0; t < T_; ++t) {
        float z = xgb[t * G_ + j] + bj;
        #pragma unroll
        for (int k = 0; k < H_; k += 4) {
            f32x4 hv = *(const f32x4*)&h_lds[k];   // same-addr broadcast, conflict-free
            z += hv[0] * U[k] + hv[1] * U[k + 1] + hv[2] * U[k + 2] + hv[3] * U[k + 3];
        }
        z_lds[j] = z;
        __syncthreads();                            // B1: z ready, h reads done
        if (j < H_) {
            float si = sigmoidf_fast(z_lds[j]);          // i
            float sf = sigmoidf_fast(z_lds[j + 128]);    // f
            float tg = tanhf_fast  (z_lds[j + 256]);     // g
            float so = sigmoidf_fast(z_lds[j + 384]);    // o
            c = sf * c + si * tg;
            h_lds[j] = so * tanhf_fast(c);
        }
        __syncthreads();                            // B2: h ready for next step
    }

    // output head: out[b] = h_f @ Wout + bout  (O_=2, trivial)
    if (j < O_) {
        float acc2 = bout[j];
        for (int k = 0; k < H_; ++k) acc2 += h_lds[k] * Wout[k * O_ + j];
        out[b * O_ + j] = acc2;
    }
}

extern "C" void kernel_launch(void* const* d_in, const int* in_sizes, int n_in,
                              void* d_out, int out_size, void* d_ws, size_t ws_size,
                              hipStream_t stream) {
    const float* x    = (const float*)d_in[0];
    const float* Wi   = (const float*)d_in[1];
    const float* Uh   = (const float*)d_in[2];
    const float* bias = (const float*)d_in[3];
    const float* Wout = (const float*)d_in[4];
    const float* bout = (const float*)d_in[5];
    float* out = (float*)d_out;

    _Float16* Wt = (_Float16*)d_ws;                                       // 2 MB
    float*    xg = (float*)((char*)d_ws + (size_t)G_ * I_ * sizeof(_Float16)); // 64 MB

    wt_kernel<<<(G_ * I_) / 256, 256, 0, stream>>>(Wi, Wt);
    gemm_xg<<<(B_ * T_ / BM) * (G_ / BN), 256, 0, stream>>>(x, Wt, xg);
    lstm_scan<<<B_, 512, 0, stream>>>(xg, Uh, bias, Wout, bout, out);
}